// Round 1
// baseline (1165.142 us; speedup 1.0000x reference)
//
#include <hip/hip_runtime.h>
#include <stdint.h>

#define NHEADS 16
#define HDIM 32
#define NTOK 64
#define NWIN_B 2048
#define MROWS (NWIN_B * NTOK)   // 131072
#define CDIM 512
#define QKVDIM 1536
#define ATT_SCALE 0.17677669529663687f

typedef __attribute__((ext_vector_type(8))) short short8;
typedef __attribute__((ext_vector_type(4))) float f32x4;

__device__ __forceinline__ unsigned short f2bf(float f) {
  unsigned int u = __float_as_uint(f);
  u += 0x7FFFu + ((u >> 16) & 1u);   // RNE
  return (unsigned short)(u >> 16);
}

__device__ __forceinline__ void gload_lds16(const unsigned short* g, unsigned short* l) {
  __builtin_amdgcn_global_load_lds(
      (const __attribute__((address_space(1))) unsigned int*)g,
      (__attribute__((address_space(3))) unsigned int*)l, 16, 0, 0);
}

// ---------- fp32 -> bf16 convert ----------
__global__ void cvt_bf16_kernel(const float* __restrict__ src,
                                unsigned short* __restrict__ dst, int n4) {
  int i = blockIdx.x * blockDim.x + threadIdx.x;
  if (i >= n4) return;
  const float4 v = ((const float4*)src)[i];
  ushort4 o;
  o.x = f2bf(v.x); o.y = f2bf(v.y); o.z = f2bf(v.z); o.w = f2bf(v.w);
  ((ushort4*)dst)[i] = o;
}

// ---------- Swin relative-position bias expansion: bias[h][row][col] ----------
__global__ void expand_bias_kernel(const float* __restrict__ table,
                                   float* __restrict__ biasx) {
  const int t = blockIdx.x * blockDim.x + threadIdx.x;   // [0, 16*64*64)
  const int col = t & 63, row = (t >> 6) & 63, h = t >> 12;
  const int idx = ((row >> 3) - (col >> 3) + 7) * 15 + ((row & 7) - (col & 7) + 7);
  biasx[t] = table[idx * NHEADS + h];
}

// ---------- C = A[M,K] @ B[N,K]^T + bias, bf16 in, OutT out (m97 structure) ----------
template <typename OutT>
__global__ __launch_bounds__(256) void gemm_bt_kernel(
    const unsigned short* __restrict__ A,
    const unsigned short* __restrict__ Bt,
    const float* __restrict__ bias,
    OutT* __restrict__ C, int M, int N, int K) {
  constexpr int BM = 128, BN = 128, BK = 64;
  __shared__ __align__(16) unsigned short As[BM * BK];
  __shared__ __align__(16) unsigned short Bs[BN * BK];

  const int tid = threadIdx.x;
  const int w = tid >> 6, lane = tid & 63;
  const int quad = lane >> 4, l16 = lane & 15;
  const int wr = w >> 1, wc = w & 1;
  const long rowBase = (long)blockIdx.y * BM;
  const long colBase = (long)blockIdx.x * BN;

  const int srow = w * 32 + (lane >> 3);  // staging row (8 rows per wave-instr)
  const int scol = (lane & 7) * 8;        // staging col chunk (8 bf16 = 16 B)

  f32x4 acc[4][4] = {};

  for (int k0 = 0; k0 < K; k0 += BK) {
#pragma unroll
    for (int i = 0; i < 4; ++i) {
      const int r = srow + i * 8;
      gload_lds16(A  + (rowBase + r) * K + k0 + scol, &As[(w * 32 + i * 8) * BK]);
      gload_lds16(Bt + (colBase + r) * K + k0 + scol, &Bs[(w * 32 + i * 8) * BK]);
    }
    __syncthreads();
#pragma unroll
    for (int kk = 0; kk < BK; kk += 32) {
      short8 aF[4], bF[4];
#pragma unroll
      for (int t = 0; t < 4; ++t)
        aF[t] = *(const short8*)&As[(wr * 64 + t * 16 + l16) * BK + kk + quad * 8];
#pragma unroll
      for (int t = 0; t < 4; ++t)
        bF[t] = *(const short8*)&Bs[(wc * 64 + t * 16 + l16) * BK + kk + quad * 8];
#pragma unroll
      for (int mt = 0; mt < 4; ++mt)
#pragma unroll
        for (int nt = 0; nt < 4; ++nt)
          acc[mt][nt] = __builtin_amdgcn_mfma_f32_16x16x32_bf16(
              aF[mt], bF[nt], acc[mt][nt], 0, 0, 0);
    }
    __syncthreads();
  }

#pragma unroll
  for (int nt = 0; nt < 4; ++nt) {
    const long col = colBase + wc * 64 + nt * 16 + l16;
    const float bv = bias[col];
#pragma unroll
    for (int mt = 0; mt < 4; ++mt) {
      const long row0 = rowBase + wr * 64 + mt * 16 + quad * 4;
#pragma unroll
      for (int r = 0; r < 4; ++r) {
        const float v = acc[mt][nt][r] + bv;
        if constexpr (sizeof(OutT) == 2)
          C[(row0 + r) * N + col] = (OutT)f2bf(v);
        else
          C[(row0 + r) * N + col] = (OutT)v;
      }
    }
  }
}

// ---------- attention: one wave per (window b, head h) ----------
__global__ __launch_bounds__(256) void attn_kernel(
    const unsigned short* __restrict__ qkv,   // [MROWS][1536] bf16
    const float* __restrict__ biasx,          // [16][64][64]
    unsigned short* __restrict__ aout) {      // [MROWS][512] bf16
  __shared__ __align__(16) unsigned short P[4][NTOK * 72];  // +8 pad per row

  const int tid = threadIdx.x;
  const int w = tid >> 6, lane = tid & 63;
  const int quad = lane >> 4, l16 = lane & 15;
  const int b = blockIdx.x >> 2;
  const int h = (blockIdx.x & 3) * 4 + w;

  const unsigned short* base = qkv + (long)b * NTOK * QKVDIM;
  const int hoff = h * HDIM;

  // Q/K A- and B-fragments straight from global (HD=32 = one MFMA K-step)
  short8 qF[4], kF[4];
#pragma unroll
  for (int t = 0; t < 4; ++t) {
    const long roff = (long)(t * 16 + l16) * QKVDIM;
    qF[t] = *(const short8*)(base + roff + hoff + quad * 8);
    kF[t] = *(const short8*)(base + roff + 512 + hoff + quad * 8);
  }

  f32x4 S[4][4];
#pragma unroll
  for (int mi = 0; mi < 4; ++mi)
#pragma unroll
    for (int ni = 0; ni < 4; ++ni) {
      f32x4 z = {0.f, 0.f, 0.f, 0.f};
      S[mi][ni] = __builtin_amdgcn_mfma_f32_16x16x32_bf16(qF[mi], kF[ni], z, 0, 0, 0);
    }

  // softmax over each full row (row = mi*16 + quad*4 + r; cols = ni*16 + l16)
  const float* bh = biasx + h * (NTOK * NTOK);
#pragma unroll
  for (int mi = 0; mi < 4; ++mi) {
#pragma unroll
    for (int r = 0; r < 4; ++r) {
      const int row = mi * 16 + quad * 4 + r;
      float vals[4], mx = -3.4e38f;
#pragma unroll
      for (int ni = 0; ni < 4; ++ni) {
        const float s = S[mi][ni][r] * ATT_SCALE + bh[row * 64 + ni * 16 + l16];
        vals[ni] = s;
        mx = fmaxf(mx, s);
      }
#pragma unroll
      for (int d = 1; d < 16; d <<= 1) mx = fmaxf(mx, __shfl_xor(mx, d));
      float sum = 0.f;
#pragma unroll
      for (int ni = 0; ni < 4; ++ni) { vals[ni] = __expf(vals[ni] - mx); sum += vals[ni]; }
#pragma unroll
      for (int d = 1; d < 16; d <<= 1) sum += __shfl_xor(sum, d);
      const float inv = 1.0f / sum;
#pragma unroll
      for (int ni = 0; ni < 4; ++ni)
        P[w][row * 72 + ni * 16 + l16] = f2bf(vals[ni] * inv);
    }
  }

  // V B-fragments: B[k=n][col=d]
  short8 vF[2][2];
#pragma unroll
  for (int kt = 0; kt < 2; ++kt)
#pragma unroll
    for (int dt = 0; dt < 2; ++dt) {
      short8 f;
#pragma unroll
      for (int j = 0; j < 8; ++j) {
        const int n = kt * 32 + quad * 8 + j;
        f[j] = (short)base[(long)n * QKVDIM + 1024 + hoff + dt * 16 + l16];
      }
      vF[kt][dt] = f;
    }

  __syncthreads();  // P LDS write -> read ordering

  f32x4 O[4][2] = {};
#pragma unroll
  for (int mi = 0; mi < 4; ++mi)
#pragma unroll
    for (int kt = 0; kt < 2; ++kt) {
      const short8 pF = *(const short8*)&P[w][(mi * 16 + l16) * 72 + kt * 32 + quad * 8];
#pragma unroll
      for (int dt = 0; dt < 2; ++dt)
        O[mi][dt] = __builtin_amdgcn_mfma_f32_16x16x32_bf16(pF, vF[kt][dt], O[mi][dt], 0, 0, 0);
    }

#pragma unroll
  for (int mi = 0; mi < 4; ++mi)
#pragma unroll
    for (int dt = 0; dt < 2; ++dt)
#pragma unroll
      for (int r = 0; r < 4; ++r) {
        const int row = mi * 16 + quad * 4 + r;
        aout[((long)b * NTOK + row) * CDIM + hoff + dt * 16 + l16] = f2bf(O[mi][dt][r]);
      }
}

extern "C" void kernel_launch(void* const* d_in, const int* in_sizes, int n_in,
                              void* d_out, int out_size, void* d_ws, size_t ws_size,
                              hipStream_t stream) {
  const float* x      = (const float*)d_in[0];
  const float* W_qkv  = (const float*)d_in[1];
  const float* b_qkv  = (const float*)d_in[2];
  const float* W_proj = (const float*)d_in[3];
  const float* b_proj = (const float*)d_in[4];
  const float* btab   = (const float*)d_in[5];

  char* ws = (char*)d_ws;
  // layout (bytes): qkv 402,653,184 | xb/aout 134,217,728 | wqkvb 1,572,864 |
  //                 wprjb 524,288 | biasx 262,144   => total 539,230,208
  unsigned short* qkv   = (unsigned short*)ws;
  unsigned short* xb    = (unsigned short*)(ws + 402653184L);
  unsigned short* aout  = xb;  // xb dead after qkv GEMM; alias to save workspace
  unsigned short* wqkvb = (unsigned short*)(ws + 402653184L + 134217728L);
  unsigned short* wprjb = (unsigned short*)(ws + 402653184L + 134217728L + 1572864L);
  float*          biasx = (float*)(ws + 402653184L + 134217728L + 1572864L + 524288L);

  cvt_bf16_kernel<<<(MROWS * CDIM) / 1024, 256, 0, stream>>>(x, xb, (MROWS * CDIM) / 4);
  cvt_bf16_kernel<<<(QKVDIM * CDIM) / 1024, 256, 0, stream>>>(W_qkv, wqkvb, (QKVDIM * CDIM) / 4);
  cvt_bf16_kernel<<<(CDIM * CDIM) / 1024, 256, 0, stream>>>(W_proj, wprjb, (CDIM * CDIM) / 4);
  expand_bias_kernel<<<(NHEADS * NTOK * NTOK) / 256, 256, 0, stream>>>(btab, biasx);

  gemm_bt_kernel<unsigned short><<<dim3(QKVDIM / 128, MROWS / 128), 256, 0, stream>>>(
      xb, wqkvb, b_qkv, qkv, MROWS, QKVDIM, CDIM);

  attn_kernel<<<NWIN_B * 4, 256, 0, stream>>>(qkv, biasx, aout);

  gemm_bt_kernel<float><<<dim3(CDIM / 128, MROWS / 128), 256, 0, stream>>>(
      aout, wprjb, b_proj, (float*)d_out, MROWS, CDIM, CDIM);
}

// Round 2
// 1011.242 us; speedup vs baseline: 1.1522x; 1.1522x over previous
//
#include <hip/hip_runtime.h>
#include <stdint.h>

#define NHEADS 16
#define HDIM 32
#define NTOK 64
#define NWIN_B 2048
#define MROWS (NWIN_B * NTOK)   // 131072
#define CDIM 512
#define QKVDIM 1536
#define ATT_SCALE 0.17677669529663687f

typedef __attribute__((ext_vector_type(8))) short short8;
typedef __attribute__((ext_vector_type(4))) float f32x4;

__device__ __forceinline__ unsigned short f2bf(float f) {
  unsigned int u = __float_as_uint(f);
  u += 0x7FFFu + ((u >> 16) & 1u);   // RNE
  return (unsigned short)(u >> 16);
}

__device__ __forceinline__ void gload_lds16(const unsigned short* g, unsigned short* l) {
  __builtin_amdgcn_global_load_lds(
      (const __attribute__((address_space(1))) unsigned int*)g,
      (__attribute__((address_space(3))) unsigned int*)l, 16, 0, 0);
}

// ---------- fp32 -> bf16 convert ----------
__global__ void cvt_bf16_kernel(const float* __restrict__ src,
                                unsigned short* __restrict__ dst, int n4) {
  int i = blockIdx.x * blockDim.x + threadIdx.x;
  if (i >= n4) return;
  const float4 v = ((const float4*)src)[i];
  ushort4 o;
  o.x = f2bf(v.x); o.y = f2bf(v.y); o.z = f2bf(v.z); o.w = f2bf(v.w);
  ((ushort4*)dst)[i] = o;
}

// ---------- Swin relative-position bias expansion: bias[h][row][col] ----------
__global__ void expand_bias_kernel(const float* __restrict__ table,
                                   float* __restrict__ biasx) {
  const int t = blockIdx.x * blockDim.x + threadIdx.x;   // [0, 16*64*64)
  const int col = t & 63, row = (t >> 6) & 63, h = t >> 12;
  const int idx = ((row >> 3) - (col >> 3) + 7) * 15 + ((row & 7) - (col & 7) + 7);
  biasx[t] = table[idx * NHEADS + h];
}

// ---------- C = A[M,K] @ B[N,K]^T + bias, bf16 in (m97 + swizzle + XCD remap) ----------
// LDS tile layout: row-major [128][BK], but within each row the 8 16B-chunks are
// stored XOR-swizzled: LDS position p of row r holds global chunk p ^ (r&7).
// Staging writes stay contiguous (global_load_lds requirement); fragment reads
// at position c^(r&7) land 16 lanes on 16 distinct chunks -> 2-way (free).
template <typename OutT>
__global__ __launch_bounds__(256) void gemm_bt_kernel(
    const unsigned short* __restrict__ A,
    const unsigned short* __restrict__ Bt,
    const float* __restrict__ bias,
    OutT* __restrict__ C, int M, int N, int K, int nxb) {
  constexpr int BM = 128, BN = 128, BK = 64;
  __shared__ __align__(16) unsigned short smem[BM * BK + BN * BK];  // 32 KB
  unsigned short* As = smem;
  unsigned short* Bs = smem + BM * BK;

  const int tid = threadIdx.x;
  const int w = tid >> 6, lane = tid & 63;
  const int quad = lane >> 4, l16 = lane & 15;
  const int wr = w >> 1, wc = w & 1;

  // XCD-aware remap: bid%8 = XCD; within an XCD sweep columns fastest so the
  // nxb blocks sharing one A-tile run back-to-back on the same L2.
  const int nyb_per_xcd = (gridDim.x / nxb) >> 3;
  const int xcd = blockIdx.x & 7;
  const int idx = blockIdx.x >> 3;
  const long rowBase = (long)(xcd * nyb_per_xcd + idx / nxb) * BM;
  const long colBase = (long)(idx % nxb) * BN;

  const int srow8 = lane >> 3;              // row within 8-row staging instr
  const int gchunk = (lane & 7) ^ srow8;    // swizzled global 16B-chunk

  const long aBase0 = (rowBase + w * 32 + srow8) * (long)K + gchunk * 8;
  const long bBase0 = (colBase + w * 32 + srow8) * (long)K + gchunk * 8;

  f32x4 acc[4][4] = {};

  for (int k0 = 0; k0 < K; k0 += BK) {
#pragma unroll
    for (int i = 0; i < 4; ++i) {
      gload_lds16(A  + aBase0 + (long)(i * 8) * K + k0, &As[(w * 32 + i * 8) * BK]);
      gload_lds16(Bt + bBase0 + (long)(i * 8) * K + k0, &Bs[(w * 32 + i * 8) * BK]);
    }
    __syncthreads();
#pragma unroll
    for (int kkc = 0; kkc < 2; ++kkc) {   // kk = kkc*32
      const int p = ((quad + kkc * 4) ^ (l16 & 7)) * 8;
      short8 aF[4], bF[4];
#pragma unroll
      for (int t = 0; t < 4; ++t)
        aF[t] = *(const short8*)&As[(wr * 64 + t * 16 + l16) * BK + p];
#pragma unroll
      for (int t = 0; t < 4; ++t)
        bF[t] = *(const short8*)&Bs[(wc * 64 + t * 16 + l16) * BK + p];
#pragma unroll
      for (int mt = 0; mt < 4; ++mt)
#pragma unroll
        for (int nt = 0; nt < 4; ++nt)
          acc[mt][nt] = __builtin_amdgcn_mfma_f32_16x16x32_bf16(
              aF[mt], bF[nt], acc[mt][nt], 0, 0, 0);
    }
    __syncthreads();
  }

  if constexpr (sizeof(OutT) == 2) {
    // repack through LDS -> 16B/lane coalesced stores
    unsigned short* Cs = smem;   // 128x128 bf16 = 32 KB, exactly As+Bs
#pragma unroll
    for (int nt = 0; nt < 4; ++nt) {
      const int col = wc * 64 + nt * 16 + l16;
      const float bv = bias[colBase + col];
#pragma unroll
      for (int mt = 0; mt < 4; ++mt) {
        const int row0 = wr * 64 + mt * 16 + quad * 4;
#pragma unroll
        for (int r = 0; r < 4; ++r)
          Cs[(row0 + r) * 128 + col] = f2bf(acc[mt][nt][r] + bv);
      }
    }
    __syncthreads();
#pragma unroll
    for (int t = 0; t < 8; ++t) {
      const int ci = t * 256 + tid;           // 2048 chunks of 16B
      const int row = ci >> 4, ch = ci & 15;
      *(short8*)((unsigned short*)C + (rowBase + row) * N + colBase + ch * 8) =
          *(const short8*)&Cs[ci * 8];
    }
  } else {
#pragma unroll
    for (int nt = 0; nt < 4; ++nt) {
      const long col = colBase + wc * 64 + nt * 16 + l16;
      const float bv = bias[col];
#pragma unroll
      for (int mt = 0; mt < 4; ++mt) {
        const long row0 = rowBase + wr * 64 + mt * 16 + quad * 4;
#pragma unroll
        for (int r = 0; r < 4; ++r)
          C[(row0 + r) * N + col] = acc[mt][nt][r] + bv;
      }
    }
  }
}

// ---------- attention: one block = one window x 4 heads, all data via LDS ----------
__global__ __launch_bounds__(256) void attn_kernel(
    const unsigned short* __restrict__ qkv,   // [MROWS][1536] bf16
    const float* __restrict__ biasx,          // [16][64][64]
    unsigned short* __restrict__ aout) {      // [MROWS][512] bf16
  // 3 tiles of 64x128 bf16 (Q,K,V head-group slabs), XOR-swizzled rows of 16
  // 16B-chunks: position p of row r holds global chunk p ^ (r&15).
  __shared__ __align__(16) unsigned short sT[3 * 64 * 128];  // 48 KB
  unsigned short* P = sT;  // overlay: P[w][64][72] after tiles consumed

  const int tid = threadIdx.x;
  const int w = tid >> 6, lane = tid & 63;
  const int quad = lane >> 4, l16 = lane & 15;
  const int b = blockIdx.x >> 2;
  const int q = blockIdx.x & 3;       // head group: heads q*4 .. q*4+3
  const int h = q * 4 + w;

  const unsigned short* base = qkv + (long)b * NTOK * QKVDIM + q * 128;

  // stage Q,K,V: wave w stages rows w*16..w*16+15 of each tile (4 rows/instr)
  const int rloc = lane >> 4;         // row within instr
  const int ch = lane & 15;           // LDS 16B-chunk position
#pragma unroll
  for (int t = 0; t < 3; ++t) {
#pragma unroll
    for (int i = 0; i < 4; ++i) {
      const int r = w * 16 + i * 4 + rloc;
      const int gc = ch ^ (r & 15);
      gload_lds16(base + (long)r * QKVDIM + t * 512 + gc * 8,
                  &sT[t * 8192 + (w * 16 + i * 4) * 128]);
    }
  }
  __syncthreads();

  // Q/K fragments (HD=32 = one MFMA K-step); head-local chunk = w*4 + quad
  short8 qF[4], kF[4];
  const int pQ = ((w * 4 + quad) ^ l16) * 8;
#pragma unroll
  for (int t = 0; t < 4; ++t) {
    qF[t] = *(const short8*)&sT[0 * 8192 + (t * 16 + l16) * 128 + pQ];
    kF[t] = *(const short8*)&sT[1 * 8192 + (t * 16 + l16) * 128 + pQ];
  }

  f32x4 S[4][4];
#pragma unroll
  for (int mi = 0; mi < 4; ++mi)
#pragma unroll
    for (int ni = 0; ni < 4; ++ni) {
      f32x4 z = {0.f, 0.f, 0.f, 0.f};
      S[mi][ni] = __builtin_amdgcn_mfma_f32_16x16x32_bf16(qF[mi], kF[ni], z, 0, 0, 0);
    }

  // V B-fragments from LDS: B[k=n][col=d], d = dt*16+l16 head-local
  short8 vF[2][2];
#pragma unroll
  for (int kt = 0; kt < 2; ++kt)
#pragma unroll
    for (int dt = 0; dt < 2; ++dt) {
      short8 f;
#pragma unroll
      for (int j = 0; j < 8; ++j) {
        const int n = kt * 32 + quad * 8 + j;
        const int c = w * 4 + dt * 2 + (l16 >> 3);
        f[j] = (short)sT[2 * 8192 + n * 128 + (c ^ (n & 15)) * 8 + (l16 & 7)];
      }
      vF[kt][dt] = f;
    }

  __syncthreads();  // all tile reads done; P may overwrite sT

  // softmax over each full row (row = mi*16 + quad*4 + r; cols = ni*16 + l16)
  const float* bh = biasx + h * (NTOK * NTOK);
#pragma unroll
  for (int mi = 0; mi < 4; ++mi) {
#pragma unroll
    for (int r = 0; r < 4; ++r) {
      const int row = mi * 16 + quad * 4 + r;
      float vals[4], mx = -3.4e38f;
#pragma unroll
      for (int ni = 0; ni < 4; ++ni) {
        const float s = S[mi][ni][r] * ATT_SCALE + bh[row * 64 + ni * 16 + l16];
        vals[ni] = s;
        mx = fmaxf(mx, s);
      }
#pragma unroll
      for (int d = 1; d < 16; d <<= 1) mx = fmaxf(mx, __shfl_xor(mx, d));
      float sum = 0.f;
#pragma unroll
      for (int ni = 0; ni < 4; ++ni) { vals[ni] = __expf(vals[ni] - mx); sum += vals[ni]; }
#pragma unroll
      for (int d = 1; d < 16; d <<= 1) sum += __shfl_xor(sum, d);
      const float inv = 1.0f / sum;
#pragma unroll
      for (int ni = 0; ni < 4; ++ni)
        P[w * 4608 + row * 72 + ni * 16 + l16] = f2bf(vals[ni] * inv);
    }
  }

  f32x4 O[4][2] = {};
#pragma unroll
  for (int mi = 0; mi < 4; ++mi)
#pragma unroll
    for (int kt = 0; kt < 2; ++kt) {
      const short8 pF = *(const short8*)&P[w * 4608 + (mi * 16 + l16) * 72 + kt * 32 + quad * 8];
#pragma unroll
      for (int dt = 0; dt < 2; ++dt)
        O[mi][dt] = __builtin_amdgcn_mfma_f32_16x16x32_bf16(pF, vF[kt][dt], O[mi][dt], 0, 0, 0);
    }

#pragma unroll
  for (int mi = 0; mi < 4; ++mi)
#pragma unroll
    for (int dt = 0; dt < 2; ++dt)
#pragma unroll
      for (int r = 0; r < 4; ++r) {
        const int row = mi * 16 + quad * 4 + r;
        aout[((long)b * NTOK + row) * CDIM + h * HDIM + dt * 16 + l16] = f2bf(O[mi][dt][r]);
      }
}

extern "C" void kernel_launch(void* const* d_in, const int* in_sizes, int n_in,
                              void* d_out, int out_size, void* d_ws, size_t ws_size,
                              hipStream_t stream) {
  const float* x      = (const float*)d_in[0];
  const float* W_qkv  = (const float*)d_in[1];
  const float* b_qkv  = (const float*)d_in[2];
  const float* W_proj = (const float*)d_in[3];
  const float* b_proj = (const float*)d_in[4];
  const float* btab   = (const float*)d_in[5];

  char* ws = (char*)d_ws;
  unsigned short* qkv   = (unsigned short*)ws;
  unsigned short* xb    = (unsigned short*)(ws + 402653184L);
  unsigned short* aout  = xb;  // xb dead after qkv GEMM; alias to save workspace
  unsigned short* wqkvb = (unsigned short*)(ws + 402653184L + 134217728L);
  unsigned short* wprjb = (unsigned short*)(ws + 402653184L + 134217728L + 1572864L);
  float*          biasx = (float*)(ws + 402653184L + 134217728L + 1572864L + 524288L);

  cvt_bf16_kernel<<<(MROWS * CDIM) / 1024, 256, 0, stream>>>(x, xb, (MROWS * CDIM) / 4);
  cvt_bf16_kernel<<<(QKVDIM * CDIM) / 1024, 256, 0, stream>>>(W_qkv, wqkvb, (QKVDIM * CDIM) / 4);
  cvt_bf16_kernel<<<(CDIM * CDIM) / 1024, 256, 0, stream>>>(W_proj, wprjb, (CDIM * CDIM) / 4);
  expand_bias_kernel<<<(NHEADS * NTOK * NTOK) / 256, 256, 0, stream>>>(btab, biasx);

  gemm_bt_kernel<unsigned short><<<(MROWS / 128) * (QKVDIM / 128), 256, 0, stream>>>(
      xb, wqkvb, b_qkv, qkv, MROWS, QKVDIM, CDIM, QKVDIM / 128);

  attn_kernel<<<NWIN_B * 4, 256, 0, stream>>>(qkv, biasx, aout);

  gemm_bt_kernel<float><<<(MROWS / 128) * (CDIM / 128), 256, 0, stream>>>(
      aout, wprjb, b_proj, (float*)d_out, MROWS, CDIM, CDIM, CDIM / 128);
}